// Round 2
// baseline (1317.012 us; speedup 1.0000x reference)
//
#include <hip/hip_runtime.h>
#include <hip/hip_bf16.h>
#include <math.h>

// ---------------------------------------------------------------------------
// WindowedDinoV2Block: LN1 -> QKV -> windowed MHA -> WO*ls1 + res -> LN2 ->
//                      GELU MLP -> *ls2 + res
// B=32, S=576, D=1024, H=16, HD=64, DFF=4096, M = B*S = 18432 rows
// All GEMMs in bf16 MFMA (16x16x32), f32 accumulate. LN/softmax in f32.
// ---------------------------------------------------------------------------

typedef __attribute__((ext_vector_type(8))) short bf16x8;   // 8 bf16 = 4 VGPRs
typedef __attribute__((ext_vector_type(4))) float f32x4;

static constexpr int S_LEN = 576;
static constexpr int D_DIM = 1024;
static constexpr int M_ROWS = 32 * 576;  // 18432

__device__ __forceinline__ unsigned short f2bf(float f) {
  unsigned u = __builtin_bit_cast(unsigned, f);
  u += 0x7FFFu + ((u >> 16) & 1u);
  return (unsigned short)(u >> 16);
}

__device__ __forceinline__ f32x4 mfma16(bf16x8 a, bf16x8 b, f32x4 c) {
  return __builtin_amdgcn_mfma_f32_16x16x32_bf16(a, b, c, 0, 0, 0);
}

__device__ __forceinline__ void gload_lds16(const void* g, void* l) {
  __builtin_amdgcn_global_load_lds(
      (const __attribute__((address_space(1))) unsigned int*)g,
      (__attribute__((address_space(3))) unsigned int*)l, 16, 0, 0);
}

// ---------------------------------------------------------------------------
// Transpose + cast f32 [R][C] -> bf16 [C][R]
// ---------------------------------------------------------------------------
__global__ __launch_bounds__(256) void transpose_cast_kernel(
    const float* __restrict__ in, unsigned short* __restrict__ out, int R, int C) {
  __shared__ float tile[32][33];
  const int bx = blockIdx.x * 32;  // col base of input
  const int by = blockIdx.y * 32;  // row base of input
  const int tx = threadIdx.x & 31, ty = threadIdx.x >> 5;  // ty: 0..7
#pragma unroll
  for (int i = 0; i < 4; ++i) {
    int r = ty + i * 8;
    tile[r][tx] = in[(size_t)(by + r) * C + bx + tx];
  }
  __syncthreads();
#pragma unroll
  for (int i = 0; i < 4; ++i) {
    int r = ty + i * 8;
    out[(size_t)(bx + r) * R + by + tx] = f2bf(tile[tx][r]);
  }
}

// ---------------------------------------------------------------------------
// LayerNorm (D=1024) f32 in -> bf16 out. One block per row, 256 threads.
// ---------------------------------------------------------------------------
__global__ __launch_bounds__(256) void ln_kernel(
    const float* __restrict__ x, const float* __restrict__ g,
    const float* __restrict__ bta, unsigned short* __restrict__ out) {
  const int row = blockIdx.x;
  const int t = threadIdx.x;
  const float* xr = x + (size_t)row * D_DIM;
  float4 v = *(const float4*)&xr[t * 4];
  float s = v.x + v.y + v.z + v.w;
  float sq = v.x * v.x + v.y * v.y + v.z * v.z + v.w * v.w;
#pragma unroll
  for (int o = 32; o; o >>= 1) {
    s += __shfl_xor(s, o);
    sq += __shfl_xor(sq, o);
  }
  __shared__ float sa[4], sb[4];
  const int wid = t >> 6, lane = t & 63;
  if (lane == 0) { sa[wid] = s; sb[wid] = sq; }
  __syncthreads();
  s = sa[0] + sa[1] + sa[2] + sa[3];
  sq = sb[0] + sb[1] + sb[2] + sb[3];
  const float mu = s * (1.0f / D_DIM);
  const float var = sq * (1.0f / D_DIM) - mu * mu;
  const float rstd = rsqrtf(var + 1e-6f);
  float4 gv = *(const float4*)&g[t * 4];
  float4 bv = *(const float4*)&bta[t * 4];
  ushort4 o4;
  o4.x = f2bf((v.x - mu) * rstd * gv.x + bv.x);
  o4.y = f2bf((v.y - mu) * rstd * gv.y + bv.y);
  o4.z = f2bf((v.z - mu) * rstd * gv.z + bv.z);
  o4.w = f2bf((v.w - mu) * rstd * gv.w + bv.w);
  *(ushort4*)&out[(size_t)row * D_DIM + t * 4] = o4;
}

// ---------------------------------------------------------------------------
// GEMM: C[M][N] = A[M][K](bf16) @ B (Bt[N][K] bf16), 128x128 tile, BK=32,
// 4 waves (2x2), each wave 64x64 via 4x4 16x16x32 MFMA fragments.
// ---------------------------------------------------------------------------
enum { EPI_BF16_BIAS = 0, EPI_F32_RES = 1, EPI_GELU = 2 };

template <int EPI>
__global__ __launch_bounds__(256) void gemm_bt(
    const unsigned short* __restrict__ A, const unsigned short* __restrict__ Bt,
    int K, int N, const float* __restrict__ bias, const float* __restrict__ ls,
    const float* __restrict__ res, unsigned short* __restrict__ outb,
    float* __restrict__ outf) {
  __shared__ __align__(16) unsigned short Al[128 * 32];
  __shared__ __align__(16) unsigned short Bl[128 * 32];
  const int m0 = blockIdx.y * 128, n0 = blockIdx.x * 128;
  const int tid = threadIdx.x, lane = tid & 63, wid = tid >> 6;
  const int wm = wid >> 1, wn = wid & 1;
  const int l15 = lane & 15, lg = lane >> 4;
  const int srow = lane >> 2;        // 0..15
  const int scol = (lane & 3) * 8;   // 0,8,16,24 (elements)

  f32x4 acc[4][4];
#pragma unroll
  for (int m = 0; m < 4; ++m)
#pragma unroll
    for (int n = 0; n < 4; ++n) acc[m][n] = (f32x4)0.0f;

  for (int k0 = 0; k0 < K; k0 += 32) {
#pragma unroll
    for (int c = 0; c < 2; ++c) {
      const int r = wid * 32 + c * 16;
      gload_lds16(A + (size_t)(m0 + r + srow) * K + k0 + scol, &Al[r * 32]);
      gload_lds16(Bt + (size_t)(n0 + r + srow) * K + k0 + scol, &Bl[r * 32]);
    }
    __syncthreads();  // drains vmcnt before barrier
    bf16x8 af[4], bfr[4];
#pragma unroll
    for (int m = 0; m < 4; ++m)
      af[m] = *(const bf16x8*)&Al[(wm * 64 + m * 16 + l15) * 32 + lg * 8];
#pragma unroll
    for (int n = 0; n < 4; ++n)
      bfr[n] = *(const bf16x8*)&Bl[(wn * 64 + n * 16 + l15) * 32 + lg * 8];
#pragma unroll
    for (int m = 0; m < 4; ++m)
#pragma unroll
      for (int n = 0; n < 4; ++n) acc[m][n] = mfma16(af[m], bfr[n], acc[m][n]);
    __syncthreads();  // all reads done before next stage overwrites
  }

#pragma unroll
  for (int m = 0; m < 4; ++m) {
    const int rowb = m0 + wm * 64 + m * 16 + lg * 4;
#pragma unroll
    for (int n = 0; n < 4; ++n) {
      const int col = n0 + wn * 64 + n * 16 + l15;
      const float bcol = bias[col];
#pragma unroll
      for (int r = 0; r < 4; ++r) {
        const int grow = rowb + r;
        const float vacc = acc[m][n][r] + bcol;
        if constexpr (EPI == EPI_BF16_BIAS) {
          outb[(size_t)grow * N + col] = f2bf(vacc);
        } else if constexpr (EPI == EPI_GELU) {
          const float gv = 0.5f * vacc * (1.0f + erff(vacc * 0.70710678118654752f));
          outb[(size_t)grow * N + col] = f2bf(gv);
        } else {
          outf[(size_t)grow * N + col] =
              vacc * ls[col] + res[(size_t)grow * N + col];
        }
      }
    }
  }
}

// ---------------------------------------------------------------------------
// Flash attention: grid (9 qblocks, B*H). Block = 4 waves; each wave owns 16
// Q-rows. 32-key tiles; K fragments direct from global; V^T staged in LDS.
// Online softmax in f32; P via per-wave LDS tile to reach MFMA A-layout.
// ---------------------------------------------------------------------------
__global__ __launch_bounds__(256) void attn_kernel(
    const unsigned short* __restrict__ q, const unsigned short* __restrict__ k,
    const unsigned short* __restrict__ v, unsigned short* __restrict__ ctx) {
  __shared__ __align__(16) unsigned short Vt[64][40];     // [hd][key] +pad
  __shared__ __align__(16) unsigned short P[4][16][40];   // per-wave P tile
  const int bh = blockIdx.y, b = bh >> 4, h = bh & 15;
  const int q0 = blockIdx.x * 64;
  const int tid = threadIdx.x, lane = tid & 63, wid = tid >> 6;
  const int l15 = lane & 15, lg = lane >> 4;
  const size_t base = (size_t)b * S_LEN * D_DIM + h * 64;

  const int qrow = q0 + wid * 16 + l15;
  const bf16x8 qf0 = *(const bf16x8*)(q + base + (size_t)qrow * D_DIM + lg * 8);
  const bf16x8 qf1 = *(const bf16x8*)(q + base + (size_t)qrow * D_DIM + 32 + lg * 8);

  f32x4 acc_o[4];
#pragma unroll
  for (int nt = 0; nt < 4; ++nt) acc_o[nt] = (f32x4)0.0f;
  float mrow[4] = {-3e38f, -3e38f, -3e38f, -3e38f};
  float lrow[4] = {0.f, 0.f, 0.f, 0.f};

  const int vkey = tid >> 3, vchunk = tid & 7;

  for (int kt = 0; kt < S_LEN / 32; ++kt) {
    __syncthreads();  // previous tile's Vt reads complete
    // stage V^T tile: V[kt*32 + key][hd] -> Vt[hd][key]
    {
      const bf16x8 vv = *(const bf16x8*)(v + base + (size_t)(kt * 32 + vkey) * D_DIM + vchunk * 8);
#pragma unroll
      for (int j = 0; j < 8; ++j) Vt[vchunk * 8 + j][vkey] = (unsigned short)vv[j];
    }
    // QK^T for 32 keys (2 n-tiles of 16)
    f32x4 s0 = (f32x4)0.0f, s1 = (f32x4)0.0f;
    {
      const size_t kr0 = base + (size_t)(kt * 32 + l15) * D_DIM;
      const size_t kr1 = base + (size_t)(kt * 32 + 16 + l15) * D_DIM;
      bf16x8 k00 = *(const bf16x8*)(k + kr0 + lg * 8);
      bf16x8 k01 = *(const bf16x8*)(k + kr0 + 32 + lg * 8);
      bf16x8 k10 = *(const bf16x8*)(k + kr1 + lg * 8);
      bf16x8 k11 = *(const bf16x8*)(k + kr1 + 32 + lg * 8);
      s0 = mfma16(qf0, k00, s0);
      s0 = mfma16(qf1, k01, s0);
      s1 = mfma16(qf0, k10, s1);
      s1 = mfma16(qf1, k11, s1);
    }
    __syncthreads();  // Vt staged & visible
    // online softmax; rows are (lg*4 + r), cols l15 (+16)
    float al[4];
#pragma unroll
    for (int r = 0; r < 4; ++r) {
      const float x0 = s0[r] * 0.125f, x1 = s1[r] * 0.125f;
      float mt = fmaxf(x0, x1);
      mt = fmaxf(mt, __shfl_xor(mt, 1));
      mt = fmaxf(mt, __shfl_xor(mt, 2));
      mt = fmaxf(mt, __shfl_xor(mt, 4));
      mt = fmaxf(mt, __shfl_xor(mt, 8));
      const float mn = fmaxf(mrow[r], mt);
      const float a = __expf(mrow[r] - mn);
      const float p0 = __expf(x0 - mn), p1 = __expf(x1 - mn);
      float rs = p0 + p1;
      rs += __shfl_xor(rs, 1);
      rs += __shfl_xor(rs, 2);
      rs += __shfl_xor(rs, 4);
      rs += __shfl_xor(rs, 8);
      lrow[r] = lrow[r] * a + rs;
      mrow[r] = mn;
      al[r] = a;
      P[wid][lg * 4 + r][l15] = f2bf(p0);
      P[wid][lg * 4 + r][l15 + 16] = f2bf(p1);
    }
#pragma unroll
    for (int nt = 0; nt < 4; ++nt) {
      f32x4 t = acc_o[nt];
      t[0] *= al[0]; t[1] *= al[1]; t[2] *= al[2]; t[3] *= al[3];
      acc_o[nt] = t;
    }
    // PV: P (A-frag) from LDS, V^T (B-frag) from LDS
    const bf16x8 pf = *(const bf16x8*)&P[wid][l15][lg * 8];
#pragma unroll
    for (int nt = 0; nt < 4; ++nt) {
      const bf16x8 vf = *(const bf16x8*)&Vt[nt * 16 + l15][lg * 8];
      acc_o[nt] = mfma16(pf, vf, acc_o[nt]);
    }
  }
  // epilogue: divide by row sum, write ctx (bf16)
#pragma unroll
  for (int nt = 0; nt < 4; ++nt) {
#pragma unroll
    for (int r = 0; r < 4; ++r) {
      const int grow = q0 + wid * 16 + lg * 4 + r;
      ctx[base + (size_t)grow * D_DIM + nt * 16 + l15] =
          f2bf(acc_o[nt][r] / lrow[r]);
    }
  }
}

// ---------------------------------------------------------------------------
extern "C" void kernel_launch(void* const* d_in, const int* in_sizes, int n_in,
                              void* d_out, int out_size, void* d_ws, size_t ws_size,
                              hipStream_t stream) {
  const float* x   = (const float*)d_in[0];
  const float* n1g = (const float*)d_in[1];
  const float* n1b = (const float*)d_in[2];
  const float* wq  = (const float*)d_in[3];
  const float* bq  = (const float*)d_in[4];
  const float* wk  = (const float*)d_in[5];
  const float* bk  = (const float*)d_in[6];
  const float* wv  = (const float*)d_in[7];
  const float* bv  = (const float*)d_in[8];
  const float* wo  = (const float*)d_in[9];
  const float* bo  = (const float*)d_in[10];
  const float* ls1 = (const float*)d_in[11];
  const float* n2g = (const float*)d_in[12];
  const float* n2b = (const float*)d_in[13];
  const float* w1  = (const float*)d_in[14];
  const float* b1  = (const float*)d_in[15];
  const float* w2  = (const float*)d_in[16];
  const float* b2  = (const float*)d_in[17];
  const float* ls2 = (const float*)d_in[18];
  float* out = (float*)d_out;

  char* ws = (char*)d_ws;
  const size_t MB = 1ull << 20;
  unsigned short* wqt = (unsigned short*)(ws + 0 * MB);    // [1024][1024]
  unsigned short* wkt = (unsigned short*)(ws + 2 * MB);
  unsigned short* wvt = (unsigned short*)(ws + 4 * MB);
  unsigned short* wot = (unsigned short*)(ws + 6 * MB);
  unsigned short* w1t = (unsigned short*)(ws + 8 * MB);    // [4096][1024]
  unsigned short* w2t = (unsigned short*)(ws + 16 * MB);   // [1024][4096]
  unsigned short* xn  = (unsigned short*)(ws + 24 * MB);   // 36MB
  unsigned short* qb  = (unsigned short*)(ws + 60 * MB);   // 36MB
  unsigned short* kb  = (unsigned short*)(ws + 96 * MB);   // 36MB
  unsigned short* vb  = (unsigned short*)(ws + 132 * MB);  // 36MB
  unsigned short* ctx = xn;                                 // reuse (xn dead)
  unsigned short* hbuf = xn;  // 144MB spans xn..vb (all dead when written)
  unsigned short* yn  = (unsigned short*)(ws + 168 * MB);  // 36MB -> total 204MB
  (void)ws_size; (void)in_sizes; (void)n_in; (void)out_size;

  const dim3 blk(256);
  // weight transpose+cast to bf16 Bt[N][K]
  transpose_cast_kernel<<<dim3(32, 32), blk, 0, stream>>>(wq, wqt, 1024, 1024);
  transpose_cast_kernel<<<dim3(32, 32), blk, 0, stream>>>(wk, wkt, 1024, 1024);
  transpose_cast_kernel<<<dim3(32, 32), blk, 0, stream>>>(wv, wvt, 1024, 1024);
  transpose_cast_kernel<<<dim3(32, 32), blk, 0, stream>>>(wo, wot, 1024, 1024);
  transpose_cast_kernel<<<dim3(128, 32), blk, 0, stream>>>(w1, w1t, 1024, 4096);
  transpose_cast_kernel<<<dim3(32, 128), blk, 0, stream>>>(w2, w2t, 4096, 1024);
  // LN1
  ln_kernel<<<dim3(M_ROWS), blk, 0, stream>>>(x, n1g, n1b, xn);
  // QKV projections
  gemm_bt<EPI_BF16_BIAS><<<dim3(8, 144), blk, 0, stream>>>(
      xn, wqt, 1024, 1024, bq, nullptr, nullptr, qb, nullptr);
  gemm_bt<EPI_BF16_BIAS><<<dim3(8, 144), blk, 0, stream>>>(
      xn, wkt, 1024, 1024, bk, nullptr, nullptr, kb, nullptr);
  gemm_bt<EPI_BF16_BIAS><<<dim3(8, 144), blk, 0, stream>>>(
      xn, wvt, 1024, 1024, bv, nullptr, nullptr, vb, nullptr);
  // attention (overwrites xn with ctx)
  attn_kernel<<<dim3(9, 512), blk, 0, stream>>>(qb, kb, vb, ctx);
  // WO + ls1 + residual -> x1 (stored in d_out)
  gemm_bt<EPI_F32_RES><<<dim3(8, 144), blk, 0, stream>>>(
      ctx, wot, 1024, 1024, bo, ls1, x, nullptr, out);
  // LN2
  ln_kernel<<<dim3(M_ROWS), blk, 0, stream>>>(out, n2g, n2b, yn);
  // W1 + GELU -> h (reuses xn/q/k/v region, exactly 144MB)
  gemm_bt<EPI_GELU><<<dim3(32, 144), blk, 0, stream>>>(
      yn, w1t, 1024, 4096, b1, nullptr, nullptr, hbuf, nullptr);
  // W2 + ls2 + residual(x1 in d_out) -> out
  gemm_bt<EPI_F32_RES><<<dim3(8, 144), blk, 0, stream>>>(
      hbuf, w2t, 4096, 1024, b2, ls2, out, nullptr, out);
}

// Round 3
// 1154.116 us; speedup vs baseline: 1.1411x; 1.1411x over previous
//
#include <hip/hip_runtime.h>
#include <hip/hip_bf16.h>
#include <math.h>

// ---------------------------------------------------------------------------
// WindowedDinoV2Block: LN1 -> fused QKV -> windowed MHA -> WO*ls1 + res ->
//                      LN2 -> GELU MLP -> *ls2 + res
// B=32, S=576, D=1024, H=16, HD=64, DFF=4096, M=18432
// GEMMs: 256x256 8-phase template (T1+T2+T3+T4+T5), bf16 MFMA 16x16x32.
// ---------------------------------------------------------------------------

typedef __attribute__((ext_vector_type(8))) short bf16x8;
typedef __attribute__((ext_vector_type(4))) float f32x4;

static constexpr int S_LEN = 576;
static constexpr int D_DIM = 1024;
static constexpr int M_ROWS = 18432;

__device__ __forceinline__ unsigned short f2bf(float f) {
  unsigned u = __builtin_bit_cast(unsigned, f);
  u += 0x7FFFu + ((u >> 16) & 1u);
  return (unsigned short)(u >> 16);
}

__device__ __forceinline__ f32x4 mfma16(bf16x8 a, bf16x8 b, f32x4 c) {
  return __builtin_amdgcn_mfma_f32_16x16x32_bf16(a, b, c, 0, 0, 0);
}

__device__ __forceinline__ void gload_lds16(const void* g, void* l) {
  __builtin_amdgcn_global_load_lds(
      (const __attribute__((address_space(1))) unsigned int*)g,
      (__attribute__((address_space(3))) unsigned int*)l, 16, 0, 0);
}

// ---------------------------------------------------------------------------
// Transpose + cast f32 [R][C] -> bf16 [C][R]
// ---------------------------------------------------------------------------
__global__ __launch_bounds__(256) void transpose_cast_kernel(
    const float* __restrict__ in, unsigned short* __restrict__ out, int R, int C) {
  __shared__ float tile[32][33];
  const int bx = blockIdx.x * 32, by = blockIdx.y * 32;
  const int tx = threadIdx.x & 31, ty = threadIdx.x >> 5;
#pragma unroll
  for (int i = 0; i < 4; ++i) {
    int r = ty + i * 8;
    tile[r][tx] = in[(size_t)(by + r) * C + bx + tx];
  }
  __syncthreads();
#pragma unroll
  for (int i = 0; i < 4; ++i) {
    int r = ty + i * 8;
    out[(size_t)(bx + r) * R + by + tx] = f2bf(tile[tx][r]);
  }
}

// Concatenate 3 bias vectors of 1024 into one 3072 vector.
__global__ __launch_bounds__(256) void concat3_kernel(
    const float* __restrict__ a, const float* __restrict__ b,
    const float* __restrict__ c, float* __restrict__ o) {
  int i = blockIdx.x * 256 + threadIdx.x;
  o[i] = (i < 1024) ? a[i] : (i < 2048 ? b[i - 1024] : c[i - 2048]);
}

// ---------------------------------------------------------------------------
// LayerNorm (D=1024) f32 in -> bf16 out. One block per row, 256 threads.
// ---------------------------------------------------------------------------
__global__ __launch_bounds__(256) void ln_kernel(
    const float* __restrict__ x, const float* __restrict__ g,
    const float* __restrict__ bta, unsigned short* __restrict__ out) {
  const int row = blockIdx.x;
  const int t = threadIdx.x;
  const float* xr = x + (size_t)row * D_DIM;
  float4 v = *(const float4*)&xr[t * 4];
  float s = v.x + v.y + v.z + v.w;
  float sq = v.x * v.x + v.y * v.y + v.z * v.z + v.w * v.w;
#pragma unroll
  for (int o = 32; o; o >>= 1) {
    s += __shfl_xor(s, o);
    sq += __shfl_xor(sq, o);
  }
  __shared__ float sa[4], sb[4];
  const int wid = t >> 6, lane = t & 63;
  if (lane == 0) { sa[wid] = s; sb[wid] = sq; }
  __syncthreads();
  s = sa[0] + sa[1] + sa[2] + sa[3];
  sq = sb[0] + sb[1] + sb[2] + sb[3];
  const float mu = s * (1.0f / D_DIM);
  const float var = sq * (1.0f / D_DIM) - mu * mu;
  const float rstd = rsqrtf(var + 1e-6f);
  float4 gv = *(const float4*)&g[t * 4];
  float4 bv = *(const float4*)&bta[t * 4];
  ushort4 o4;
  o4.x = f2bf((v.x - mu) * rstd * gv.x + bv.x);
  o4.y = f2bf((v.y - mu) * rstd * gv.y + bv.y);
  o4.z = f2bf((v.z - mu) * rstd * gv.z + bv.z);
  o4.w = f2bf((v.w - mu) * rstd * gv.w + bv.w);
  *(ushort4*)&out[(size_t)row * D_DIM + t * 4] = o4;
}

// ---------------------------------------------------------------------------
// 256x256 8-phase GEMM (BK=64, 512 thr, 8 waves 2Mx4N, dbuf LDS 128KB).
// A[M][K] bf16, Bt[N][K] bf16. Swizzled LDS slots via pre-swizzled global src.
// Phase: {ds-read frags | stage 1 half-tile | barrier | lgkmcnt(0) |
//         setprio(1) 16xMFMA setprio(0) | [vmcnt] | barrier}
// Staging schedule (iter consumes T from buf0 at P1-4, T+1 from buf1 at P5-8):
//   P1:(T+1).A.H0->As1  P2:(T+1).A.H1->As1  P3:(T+2).B.H0->Bs0  P4:(T+2).B.H1->Bs0
//   P5:(T+2).A.H0->As0  P6:(T+2).A.H1->As0  P7:(T+3).B.H0->Bs1  P8:(T+3).B.H1->Bs1
// vmcnt(4) at P4 (vmcnt(0) last iter) and P8. All WAR/RAW windows verified.
// ---------------------------------------------------------------------------
enum { EPI_BF16_BIAS = 0, EPI_F32_RES = 1, EPI_GELU = 2 };

#define VM4 asm volatile("s_waitcnt vmcnt(4)" ::: "memory");
#define VM0 asm volatile("s_waitcnt vmcnt(0)" ::: "memory");

#define STAGE(GPTR, BASE, LDK, KT, H, LDSBASE)                                \
  if ((KT) < NT) {                                                            \
    const int rb_ = (H) * 128 + wid * 16;                                     \
    gload_lds16((GPTR) + (size_t)((BASE) + rb_ + rlo) * (LDK) +               \
                    (size_t)(KT) * 64 + slsw * 8,                             \
                (LDSBASE) + rb_ * 64);                                        \
    gload_lds16((GPTR) + (size_t)((BASE) + rb_ + 8 + rlo) * (LDK) +           \
                    (size_t)(KT) * 64 + slsw * 8,                             \
                (LDSBASE) + (rb_ + 8) * 64);                                  \
  }

#define PHASE(AP, BP, Q, VMSTMT, ...)                                         \
  {                                                                           \
    _Pragma("unroll") for (int mm = 0; mm < 2; ++mm)                          \
      _Pragma("unroll") for (int ks = 0; ks < 2; ++ks)                        \
        af[mm][ks] = *(const bf16x8*)((AP) + (2 * (Q) + mm) * 1024 +          \
                                      (((ks * 4 + lg) ^ l7) * 8));            \
    if ((Q) == 0) {                                                           \
      _Pragma("unroll") for (int n = 0; n < 4; ++n)                           \
        _Pragma("unroll") for (int ks = 0; ks < 2; ++ks)                      \
          bfr[n][ks] = *(const bf16x8*)((BP) + n * 1024 +                     \
                                        (((ks * 4 + lg) ^ l7) * 8));          \
    }                                                                         \
    __VA_ARGS__;                                                              \
    __builtin_amdgcn_s_barrier();                                             \
    asm volatile("s_waitcnt lgkmcnt(0)" ::: "memory");                        \
    __builtin_amdgcn_sched_barrier(0);                                        \
    __builtin_amdgcn_s_setprio(1);                                            \
    _Pragma("unroll") for (int mm = 0; mm < 2; ++mm)                          \
      _Pragma("unroll") for (int n = 0; n < 4; ++n) {                         \
        acc[2 * (Q) + mm][n] = mfma16(af[mm][0], bfr[n][0], acc[2*(Q)+mm][n]);\
        acc[2 * (Q) + mm][n] = mfma16(af[mm][1], bfr[n][1], acc[2*(Q)+mm][n]);\
      }                                                                       \
    __builtin_amdgcn_s_setprio(0);                                            \
    VMSTMT;                                                                   \
    __builtin_amdgcn_s_barrier();                                             \
  }

template <int EPI>
__global__ __launch_bounds__(512, 2) void gemm256(
    const unsigned short* __restrict__ A, const unsigned short* __restrict__ Bt,
    const int K, const int N, const int NN,
    const float* __restrict__ bias, const float* __restrict__ ls,
    const float* __restrict__ res, unsigned short* __restrict__ outb,
    float* __restrict__ outf) {
  __shared__ __align__(16) unsigned short As[2][256 * 64];
  __shared__ __align__(16) unsigned short Bs[2][256 * 64];

  // T1: bijective XCD swizzle (m204); row-major tiles (n fastest) for A reuse.
  const int nwg = gridDim.x;
  const int orig = blockIdx.x;
  const int q8 = nwg >> 3, r8 = nwg & 7;
  const int xcd = orig & 7, lid = orig >> 3;
  const int swz =
      (xcd < r8 ? xcd * (q8 + 1) : r8 * (q8 + 1) + (xcd - r8) * q8) + lid;
  const int m0 = (swz / NN) * 256, n0 = (swz % NN) * 256;

  const int tid = threadIdx.x, lane = tid & 63, wid = tid >> 6;
  const int wm = wid >> 2, wn = wid & 3;
  const int l15 = lane & 15, lg = lane >> 4, l7 = lane & 7;
  const int rlo = lane >> 3;          // staging: row within 8-row group
  const int slsw = (lane & 7) ^ rlo;  // staging: pre-swizzled logical slot

  const unsigned short* Ap0 = &As[0][0] + (wm * 128 + l15) * 64;
  const unsigned short* Ap1 = &As[1][0] + (wm * 128 + l15) * 64;
  const unsigned short* Bp0 = &Bs[0][0] + (wn * 64 + l15) * 64;
  const unsigned short* Bp1 = &Bs[1][0] + (wn * 64 + l15) * 64;

  const int NT = K >> 6;  // 64-wide K-tiles (even for all our K)

  f32x4 acc[8][4];
#pragma unroll
  for (int m = 0; m < 8; ++m)
#pragma unroll
    for (int n = 0; n < 4; ++n) acc[m][n] = (f32x4)0.0f;
  bf16x8 af[2][2], bfr[4][2];

  // prologue: T0 fully, T1.B; leave T1.B (4 loads) in flight
  STAGE(A, m0, K, 0, 0, &As[0][0]);
  STAGE(A, m0, K, 0, 1, &As[0][0]);
  STAGE(Bt, n0, K, 0, 0, &Bs[0][0]);
  STAGE(Bt, n0, K, 0, 1, &Bs[0][0]);
  STAGE(Bt, n0, K, 1, 0, &Bs[1][0]);
  STAGE(Bt, n0, K, 1, 1, &Bs[1][0]);
  VM4;
  __builtin_amdgcn_s_barrier();

  const int NIT = NT >> 1;
  for (int it = 0; it < NIT; ++it) {
    const int T = it * 2;
    const bool last = (it == NIT - 1);
    PHASE(Ap0, Bp0, 0, , STAGE(A, m0, K, T + 1, 0, &As[1][0]))
    PHASE(Ap0, Bp0, 1, , STAGE(A, m0, K, T + 1, 1, &As[1][0]))
    PHASE(Ap0, Bp0, 2, , STAGE(Bt, n0, K, T + 2, 0, &Bs[0][0]))
    PHASE(Ap0, Bp0, 3, if (last) { VM0 } else { VM4 },
          STAGE(Bt, n0, K, T + 2, 1, &Bs[0][0]))
    PHASE(Ap1, Bp1, 0, , STAGE(A, m0, K, T + 2, 0, &As[0][0]))
    PHASE(Ap1, Bp1, 1, , STAGE(A, m0, K, T + 2, 1, &As[0][0]))
    PHASE(Ap1, Bp1, 2, , STAGE(Bt, n0, K, T + 3, 0, &Bs[1][0]))
    PHASE(Ap1, Bp1, 3, VM4, STAGE(Bt, n0, K, T + 3, 1, &Bs[1][0]))
  }

  // epilogue
  const int rowbase = m0 + wm * 128 + lg * 4;
  const int colbase = n0 + wn * 64 + l15;
#pragma unroll
  for (int m = 0; m < 8; ++m) {
#pragma unroll
    for (int n = 0; n < 4; ++n) {
      const int col = colbase + n * 16;
      const float bcol = bias[col];
#pragma unroll
      for (int r = 0; r < 4; ++r) {
        const int grow = rowbase + m * 16 + r;
        const float vacc = acc[m][n][r] + bcol;
        if constexpr (EPI == EPI_BF16_BIAS) {
          outb[(size_t)grow * N + col] = f2bf(vacc);
        } else if constexpr (EPI == EPI_GELU) {
          const float gv =
              0.5f * vacc * (1.0f + erff(vacc * 0.70710678118654752f));
          outb[(size_t)grow * N + col] = f2bf(gv);
        } else {
          outf[(size_t)grow * N + col] =
              vacc * ls[col] + res[(size_t)grow * N + col];
        }
      }
    }
  }
}

// ---------------------------------------------------------------------------
// Flash attention over fused QKV [M][3072]: grid (9 qblocks, B*H).
// 4 waves x 16 Q-rows; 32-key tiles; K frags direct from global; V^T in LDS.
// ---------------------------------------------------------------------------
__global__ __launch_bounds__(256) void attn_kernel(
    const unsigned short* __restrict__ qkv, unsigned short* __restrict__ ctx) {
  __shared__ __align__(16) unsigned short Vt[64][40];
  __shared__ __align__(16) unsigned short P[4][16][40];
  const int bh = blockIdx.y, b = bh >> 4, h = bh & 15;
  const int q0 = blockIdx.x * 64;
  const int tid = threadIdx.x, lane = tid & 63, wid = tid >> 6;
  const int l15 = lane & 15, lg = lane >> 4;
  const size_t base = (size_t)b * S_LEN * 3072 + h * 64;
  const unsigned short* q = qkv + base;
  const unsigned short* k = qkv + base + 1024;
  const unsigned short* v = qkv + base + 2048;

  const int qrow = q0 + wid * 16 + l15;
  const bf16x8 qf0 = *(const bf16x8*)(q + (size_t)qrow * 3072 + lg * 8);
  const bf16x8 qf1 = *(const bf16x8*)(q + (size_t)qrow * 3072 + 32 + lg * 8);

  f32x4 acc_o[4];
#pragma unroll
  for (int nt = 0; nt < 4; ++nt) acc_o[nt] = (f32x4)0.0f;
  float mrow[4] = {-3e38f, -3e38f, -3e38f, -3e38f};
  float lrow[4] = {0.f, 0.f, 0.f, 0.f};

  const int vkey = tid >> 3, vchunk = tid & 7;

  for (int kt = 0; kt < S_LEN / 32; ++kt) {
    __syncthreads();
    {
      const bf16x8 vv =
          *(const bf16x8*)(v + (size_t)(kt * 32 + vkey) * 3072 + vchunk * 8);
#pragma unroll
      for (int j = 0; j < 8; ++j) Vt[vchunk * 8 + j][vkey] = (unsigned short)vv[j];
    }
    f32x4 s0 = (f32x4)0.0f, s1 = (f32x4)0.0f;
    {
      const size_t kr0 = (size_t)(kt * 32 + l15) * 3072;
      const size_t kr1 = (size_t)(kt * 32 + 16 + l15) * 3072;
      bf16x8 k00 = *(const bf16x8*)(k + kr0 + lg * 8);
      bf16x8 k01 = *(const bf16x8*)(k + kr0 + 32 + lg * 8);
      bf16x8 k10 = *(const bf16x8*)(k + kr1 + lg * 8);
      bf16x8 k11 = *(const bf16x8*)(k + kr1 + 32 + lg * 8);
      s0 = mfma16(qf0, k00, s0);
      s0 = mfma16(qf1, k01, s0);
      s1 = mfma16(qf0, k10, s1);
      s1 = mfma16(qf1, k11, s1);
    }
    __syncthreads();
    float al[4];
#pragma unroll
    for (int r = 0; r < 4; ++r) {
      const float x0 = s0[r] * 0.125f, x1 = s1[r] * 0.125f;
      float mt = fmaxf(x0, x1);
      mt = fmaxf(mt, __shfl_xor(mt, 1));
      mt = fmaxf(mt, __shfl_xor(mt, 2));
      mt = fmaxf(mt, __shfl_xor(mt, 4));
      mt = fmaxf(mt, __shfl_xor(mt, 8));
      const float mn = fmaxf(mrow[r], mt);
      const float a = __expf(mrow[r] - mn);
      const float p0 = __expf(x0 - mn), p1 = __expf(x1 - mn);
      float rs = p0 + p1;
      rs += __shfl_xor(rs, 1);
      rs += __shfl_xor(rs, 2);
      rs += __shfl_xor(rs, 4);
      rs += __shfl_xor(rs, 8);
      lrow[r] = lrow[r] * a + rs;
      mrow[r] = mn;
      al[r] = a;
      P[wid][lg * 4 + r][l15] = f2bf(p0);
      P[wid][lg * 4 + r][l15 + 16] = f2bf(p1);
    }
#pragma unroll
    for (int nt = 0; nt < 4; ++nt) {
      f32x4 t = acc_o[nt];
      t[0] *= al[0]; t[1] *= al[1]; t[2] *= al[2]; t[3] *= al[3];
      acc_o[nt] = t;
    }
    const bf16x8 pf = *(const bf16x8*)&P[wid][l15][lg * 8];
#pragma unroll
    for (int nt = 0; nt < 4; ++nt) {
      const bf16x8 vf = *(const bf16x8*)&Vt[nt * 16 + l15][lg * 8];
      acc_o[nt] = mfma16(pf, vf, acc_o[nt]);
    }
  }
#pragma unroll
  for (int nt = 0; nt < 4; ++nt) {
#pragma unroll
    for (int r = 0; r < 4; ++r) {
      const int grow = q0 + wid * 16 + lg * 4 + r;
      ctx[(size_t)(b * S_LEN + grow) * 1024 + h * 64 + nt * 16 + l15] =
          f2bf(acc_o[nt][r] / lrow[r]);
    }
  }
}

// ---------------------------------------------------------------------------
extern "C" void kernel_launch(void* const* d_in, const int* in_sizes, int n_in,
                              void* d_out, int out_size, void* d_ws, size_t ws_size,
                              hipStream_t stream) {
  const float* x   = (const float*)d_in[0];
  const float* n1g = (const float*)d_in[1];
  const float* n1b = (const float*)d_in[2];
  const float* wq  = (const float*)d_in[3];
  const float* bq  = (const float*)d_in[4];
  const float* wk  = (const float*)d_in[5];
  const float* bk  = (const float*)d_in[6];
  const float* wv  = (const float*)d_in[7];
  const float* bv  = (const float*)d_in[8];
  const float* wo  = (const float*)d_in[9];
  const float* bo  = (const float*)d_in[10];
  const float* ls1 = (const float*)d_in[11];
  const float* n2g = (const float*)d_in[12];
  const float* n2b = (const float*)d_in[13];
  const float* w1  = (const float*)d_in[14];
  const float* b1  = (const float*)d_in[15];
  const float* w2  = (const float*)d_in[16];
  const float* b2  = (const float*)d_in[17];
  const float* ls2 = (const float*)d_in[18];
  float* out = (float*)d_out;

  char* ws = (char*)d_ws;
  // layout (bytes), total = 213909504 (204 MB, same as validated round 0):
  unsigned short* wqkvt = (unsigned short*)(ws + 0);          // [3072][1024] 6MB
  unsigned short* wot   = (unsigned short*)(ws + 6291456);    // [1024][1024] 2MB
  unsigned short* w1t   = (unsigned short*)(ws + 8388608);    // [4096][1024] 8MB
  unsigned short* w2t   = (unsigned short*)(ws + 16777216);   // [1024][4096] 8MB
  unsigned short* xn    = (unsigned short*)(ws + 25165824);   // [M][1024] 36MB
  unsigned short* qkvb  = (unsigned short*)(ws + 62914560);   // [M][3072] 108MB
  unsigned short* yn    = (unsigned short*)(ws + 176160768);  // [M][1024] 36MB
  float*          bqkv  = (float*)(ws + 176160768);           // aliases yn head (dead before LN2)
  unsigned short* ctx   = xn;    // xn dead after QKV
  unsigned short* hbuf  = xn;    // [M][4096] 144MB spans xn+qkvb (both dead by W1)
  (void)ws_size; (void)in_sizes; (void)n_in; (void)out_size;

  const dim3 blk(256);
  concat3_kernel<<<dim3(12), blk, 0, stream>>>(bq, bk, bv, bqkv);
  transpose_cast_kernel<<<dim3(32, 32), blk, 0, stream>>>(wq, wqkvt, 1024, 1024);
  transpose_cast_kernel<<<dim3(32, 32), blk, 0, stream>>>(wk, wqkvt + 1024 * 1024, 1024, 1024);
  transpose_cast_kernel<<<dim3(32, 32), blk, 0, stream>>>(wv, wqkvt + 2048 * 1024, 1024, 1024);
  transpose_cast_kernel<<<dim3(32, 32), blk, 0, stream>>>(wo, wot, 1024, 1024);
  transpose_cast_kernel<<<dim3(128, 32), blk, 0, stream>>>(w1, w1t, 1024, 4096);
  transpose_cast_kernel<<<dim3(32, 128), blk, 0, stream>>>(w2, w2t, 4096, 1024);
  ln_kernel<<<dim3(M_ROWS), blk, 0, stream>>>(x, n1g, n1b, xn);
  // fused QKV: [M][1024] @ [1024][3072] -> [M][3072]
  gemm256<EPI_BF16_BIAS><<<dim3(72 * 12), dim3(512), 0, stream>>>(
      xn, wqkvt, 1024, 3072, 12, bqkv, nullptr, nullptr, qkvb, nullptr);
  attn_kernel<<<dim3(9, 512), blk, 0, stream>>>(qkvb, ctx);
  // WO + ls1 + residual -> d_out (f32)
  gemm256<EPI_F32_RES><<<dim3(72 * 4), dim3(512), 0, stream>>>(
      ctx, wot, 1024, 1024, 4, bo, ls1, x, nullptr, out);
  ln_kernel<<<dim3(M_ROWS), blk, 0, stream>>>(out, n2g, n2b, yn);
  // W1 + exact GELU -> hbuf (bf16)
  gemm256<EPI_GELU><<<dim3(72 * 16), dim3(512), 0, stream>>>(
      yn, w1t, 1024, 4096, 16, b1, nullptr, nullptr, hbuf, nullptr);
  // W2 + ls2 + residual(d_out) -> d_out
  gemm256<EPI_F32_RES><<<dim3(72 * 4), dim3(512), 0, stream>>>(
      hbuf, w2t, 4096, 1024, 4, b2, ls2, out, nullptr, out);
}

// Round 6
// 1113.816 us; speedup vs baseline: 1.1824x; 1.0362x over previous
//
#include <hip/hip_runtime.h>
#include <hip/hip_bf16.h>
#include <math.h>

// ---------------------------------------------------------------------------
// WindowedDinoV2Block: LN1 -> fused QKV -> windowed MHA -> WO*ls1 + res ->
//                      LN2 -> GELU MLP -> *ls2 + res
// B=32, S=576, D=1024, H=16, HD=64, DFF=4096, M=18432
// GEMMs: 256x256 8-phase template (T1+T2+T3+T4+T5), bf16 MFMA 16x16x32.
// Attention: swapped QK^T (lane-local softmax) + swapped PV with V^T staged
// via validated scalar-transpose LDS path (round-2) — no tr_read.
// ---------------------------------------------------------------------------

typedef __attribute__((ext_vector_type(8))) short bf16x8;
typedef __attribute__((ext_vector_type(4))) float f32x4;
typedef __attribute__((ext_vector_type(4))) unsigned int u32x4;

static constexpr int S_LEN = 576;
static constexpr int D_DIM = 1024;
static constexpr int M_ROWS = 18432;

__device__ __forceinline__ unsigned short f2bf(float f) {
  unsigned u = __builtin_bit_cast(unsigned, f);
  u += 0x7FFFu + ((u >> 16) & 1u);
  return (unsigned short)(u >> 16);
}

__device__ __forceinline__ f32x4 mfma16(bf16x8 a, bf16x8 b, f32x4 c) {
  return __builtin_amdgcn_mfma_f32_16x16x32_bf16(a, b, c, 0, 0, 0);
}

__device__ __forceinline__ void gload_lds16(const void* g, void* l) {
  __builtin_amdgcn_global_load_lds(
      (const __attribute__((address_space(1))) unsigned int*)g,
      (__attribute__((address_space(3))) unsigned int*)l, 16, 0, 0);
}

__device__ __forceinline__ unsigned cvtpk_bf16(float lo, float hi) {
  unsigned r;
  asm("v_cvt_pk_bf16_f32 %0, %1, %2" : "=v"(r) : "v"(lo), "v"(hi));
  return r;
}

// ---------------------------------------------------------------------------
// Transpose + cast f32 [R][C] -> bf16 [C][R]
// ---------------------------------------------------------------------------
__global__ __launch_bounds__(256) void transpose_cast_kernel(
    const float* __restrict__ in, unsigned short* __restrict__ out, int R, int C) {
  __shared__ float tile[32][33];
  const int bx = blockIdx.x * 32, by = blockIdx.y * 32;
  const int tx = threadIdx.x & 31, ty = threadIdx.x >> 5;
#pragma unroll
  for (int i = 0; i < 4; ++i) {
    int r = ty + i * 8;
    tile[r][tx] = in[(size_t)(by + r) * C + bx + tx];
  }
  __syncthreads();
#pragma unroll
  for (int i = 0; i < 4; ++i) {
    int r = ty + i * 8;
    out[(size_t)(bx + r) * R + by + tx] = f2bf(tile[tx][r]);
  }
}

// Concatenate 3 bias vectors of 1024 into one 3072 vector.
__global__ __launch_bounds__(256) void concat3_kernel(
    const float* __restrict__ a, const float* __restrict__ b,
    const float* __restrict__ c, float* __restrict__ o) {
  int i = blockIdx.x * 256 + threadIdx.x;
  o[i] = (i < 1024) ? a[i] : (i < 2048 ? b[i - 1024] : c[i - 2048]);
}

// ---------------------------------------------------------------------------
// LayerNorm (D=1024) f32 in -> bf16 out. One block per row, 256 threads.
// ---------------------------------------------------------------------------
__global__ __launch_bounds__(256) void ln_kernel(
    const float* __restrict__ x, const float* __restrict__ g,
    const float* __restrict__ bta, unsigned short* __restrict__ out) {
  const int row = blockIdx.x;
  const int t = threadIdx.x;
  const float* xr = x + (size_t)row * D_DIM;
  float4 v = *(const float4*)&xr[t * 4];
  float s = v.x + v.y + v.z + v.w;
  float sq = v.x * v.x + v.y * v.y + v.z * v.z + v.w * v.w;
#pragma unroll
  for (int o = 32; o; o >>= 1) {
    s += __shfl_xor(s, o);
    sq += __shfl_xor(sq, o);
  }
  __shared__ float sa[4], sb[4];
  const int wid = t >> 6, lane = t & 63;
  if (lane == 0) { sa[wid] = s; sb[wid] = sq; }
  __syncthreads();
  s = sa[0] + sa[1] + sa[2] + sa[3];
  sq = sb[0] + sb[1] + sb[2] + sb[3];
  const float mu = s * (1.0f / D_DIM);
  const float var = sq * (1.0f / D_DIM) - mu * mu;
  const float rstd = rsqrtf(var + 1e-6f);
  float4 gv = *(const float4*)&g[t * 4];
  float4 bv = *(const float4*)&bta[t * 4];
  ushort4 o4;
  o4.x = f2bf((v.x - mu) * rstd * gv.x + bv.x);
  o4.y = f2bf((v.y - mu) * rstd * gv.y + bv.y);
  o4.z = f2bf((v.z - mu) * rstd * gv.z + bv.z);
  o4.w = f2bf((v.w - mu) * rstd * gv.w + bv.w);
  *(ushort4*)&out[(size_t)row * D_DIM + t * 4] = o4;
}

// ---------------------------------------------------------------------------
// 256x256 8-phase GEMM (BK=64, 512 thr, 8 waves 2Mx4N, dbuf LDS 128KB).
// (unchanged — verified passing in round 3)
// ---------------------------------------------------------------------------
enum { EPI_BF16_BIAS = 0, EPI_F32_RES = 1, EPI_GELU = 2 };

#define VM4 asm volatile("s_waitcnt vmcnt(4)" ::: "memory");
#define VM0 asm volatile("s_waitcnt vmcnt(0)" ::: "memory");

#define STAGE(GPTR, BASE, LDK, KT, H, LDSBASE)                                \
  if ((KT) < NT) {                                                            \
    const int rb_ = (H) * 128 + wid * 16;                                     \
    gload_lds16((GPTR) + (size_t)((BASE) + rb_ + rlo) * (LDK) +               \
                    (size_t)(KT) * 64 + slsw * 8,                             \
                (LDSBASE) + rb_ * 64);                                        \
    gload_lds16((GPTR) + (size_t)((BASE) + rb_ + 8 + rlo) * (LDK) +           \
                    (size_t)(KT) * 64 + slsw * 8,                             \
                (LDSBASE) + (rb_ + 8) * 64);                                  \
  }

#define PHASE(AP, BP, Q, VMSTMT, ...)                                         \
  {                                                                           \
    _Pragma("unroll") for (int mm = 0; mm < 2; ++mm)                          \
      _Pragma("unroll") for (int ks = 0; ks < 2; ++ks)                        \
        af[mm][ks] = *(const bf16x8*)((AP) + (2 * (Q) + mm) * 1024 +          \
                                      (((ks * 4 + lg) ^ l7) * 8));            \
    if ((Q) == 0) {                                                           \
      _Pragma("unroll") for (int n = 0; n < 4; ++n)                           \
        _Pragma("unroll") for (int ks = 0; ks < 2; ++ks)                      \
          bfr[n][ks] = *(const bf16x8*)((BP) + n * 1024 +                     \
                                        (((ks * 4 + lg) ^ l7) * 8));          \
    }                                                                         \
    __VA_ARGS__;                                                              \
    __builtin_amdgcn_s_barrier();                                             \
    asm volatile("s_waitcnt lgkmcnt(0)" ::: "memory");                        \
    __builtin_amdgcn_sched_barrier(0);                                        \
    __builtin_amdgcn_s_setprio(1);                                            \
    _Pragma("unroll") for (int mm = 0; mm < 2; ++mm)                          \
      _Pragma("unroll") for (int n = 0; n < 4; ++n) {                         \
        acc[2 * (Q) + mm][n] = mfma16(af[mm][0], bfr[n][0], acc[2*(Q)+mm][n]);\
        acc[2 * (Q) + mm][n] = mfma16(af[mm][1], bfr[n][1], acc[2*(Q)+mm][n]);\
      }                                                                       \
    __builtin_amdgcn_s_setprio(0);                                            \
    VMSTMT;                                                                   \
    __builtin_amdgcn_s_barrier();                                             \
  }

template <int EPI>
__global__ __launch_bounds__(512, 2) void gemm256(
    const unsigned short* __restrict__ A, const unsigned short* __restrict__ Bt,
    const int K, const int N, const int NN,
    const float* __restrict__ bias, const float* __restrict__ ls,
    const float* __restrict__ res, unsigned short* __restrict__ outb,
    float* __restrict__ outf) {
  __shared__ __align__(16) unsigned short As[2][256 * 64];
  __shared__ __align__(16) unsigned short Bs[2][256 * 64];

  const int nwg = gridDim.x;
  const int orig = blockIdx.x;
  const int q8 = nwg >> 3, r8 = nwg & 7;
  const int xcd = orig & 7, lid = orig >> 3;
  const int swz =
      (xcd < r8 ? xcd * (q8 + 1) : r8 * (q8 + 1) + (xcd - r8) * q8) + lid;
  const int m0 = (swz / NN) * 256, n0 = (swz % NN) * 256;

  const int tid = threadIdx.x, lane = tid & 63, wid = tid >> 6;
  const int wm = wid >> 2, wn = wid & 3;
  const int l15 = lane & 15, lg = lane >> 4, l7 = lane & 7;
  const int rlo = lane >> 3;
  const int slsw = (lane & 7) ^ rlo;

  const unsigned short* Ap0 = &As[0][0] + (wm * 128 + l15) * 64;
  const unsigned short* Ap1 = &As[1][0] + (wm * 128 + l15) * 64;
  const unsigned short* Bp0 = &Bs[0][0] + (wn * 64 + l15) * 64;
  const unsigned short* Bp1 = &Bs[1][0] + (wn * 64 + l15) * 64;

  const int NT = K >> 6;

  f32x4 acc[8][4];
#pragma unroll
  for (int m = 0; m < 8; ++m)
#pragma unroll
    for (int n = 0; n < 4; ++n) acc[m][n] = (f32x4)0.0f;
  bf16x8 af[2][2], bfr[4][2];

  STAGE(A, m0, K, 0, 0, &As[0][0]);
  STAGE(A, m0, K, 0, 1, &As[0][0]);
  STAGE(Bt, n0, K, 0, 0, &Bs[0][0]);
  STAGE(Bt, n0, K, 0, 1, &Bs[0][0]);
  STAGE(Bt, n0, K, 1, 0, &Bs[1][0]);
  STAGE(Bt, n0, K, 1, 1, &Bs[1][0]);
  VM4;
  __builtin_amdgcn_s_barrier();

  const int NIT = NT >> 1;
  for (int it = 0; it < NIT; ++it) {
    const int T = it * 2;
    const bool last = (it == NIT - 1);
    PHASE(Ap0, Bp0, 0, , STAGE(A, m0, K, T + 1, 0, &As[1][0]))
    PHASE(Ap0, Bp0, 1, , STAGE(A, m0, K, T + 1, 1, &As[1][0]))
    PHASE(Ap0, Bp0, 2, , STAGE(Bt, n0, K, T + 2, 0, &Bs[0][0]))
    PHASE(Ap0, Bp0, 3, if (last) { VM0 } else { VM4 },
          STAGE(Bt, n0, K, T + 2, 1, &Bs[0][0]))
    PHASE(Ap1, Bp1, 0, , STAGE(A, m0, K, T + 2, 0, &As[0][0]))
    PHASE(Ap1, Bp1, 1, , STAGE(A, m0, K, T + 2, 1, &As[0][0]))
    PHASE(Ap1, Bp1, 2, , STAGE(Bt, n0, K, T + 3, 0, &Bs[1][0]))
    PHASE(Ap1, Bp1, 3, VM4, STAGE(Bt, n0, K, T + 3, 1, &Bs[1][0]))
  }

  const int rowbase = m0 + wm * 128 + lg * 4;
  const int colbase = n0 + wn * 64 + l15;
#pragma unroll
  for (int m = 0; m < 8; ++m) {
#pragma unroll
    for (int n = 0; n < 4; ++n) {
      const int col = colbase + n * 16;
      const float bcol = bias[col];
#pragma unroll
      for (int r = 0; r < 4; ++r) {
        const int grow = rowbase + m * 16 + r;
        const float vacc = acc[m][n][r] + bcol;
        if constexpr (EPI == EPI_BF16_BIAS) {
          outb[(size_t)grow * N + col] = f2bf(vacc);
        } else if constexpr (EPI == EPI_GELU) {
          const float gv =
              0.5f * vacc * (1.0f + erff(vacc * 0.70710678118654752f));
          outb[(size_t)grow * N + col] = f2bf(gv);
        } else {
          outf[(size_t)grow * N + col] =
              vacc * ls[col] + res[(size_t)grow * N + col];
        }
      }
    }
  }
}

// ---------------------------------------------------------------------------
// Flash attention, swapped-operand form. Grid (9 qblocks, B*H), 4 waves.
// Wave owns 16 q-rows. Per 32-key tile:
//   S^T = mfma(K_frag, Q_frag): lane (q=l15, lg) holds S[q][k] for
//   k in {4lg..4lg+3} u {16+4lg..16+4lg+3} -> lane-local softmax (2 shfl
//   per reduce), P packed to bf16 pairs (cvt_pk), redistributed (8 shfl)
//   into the P^T B-fragment (k=8lg..8lg+7 of own q).
//   O^T += mfma(V^T_frag, P^T_frag), V^T from LDS Vt[64][40] staged by the
//   round-2-validated scalar transpose; A-frag read = ds_read_b128 at
//   Vt[nt*16+l15][lg*8] (identical indexing to round-2's passing B-frag).
// ---------------------------------------------------------------------------
__global__ __launch_bounds__(256) void attn_kernel(
    const unsigned short* __restrict__ qkv, unsigned short* __restrict__ ctx) {
  __shared__ __align__(16) unsigned short Vt[64][40];  // [hd][key] +pad
  const int bh = blockIdx.y, b = bh >> 4, h = bh & 15;
  const int q0 = blockIdx.x * 64;
  const int tid = threadIdx.x, lane = tid & 63, wid = tid >> 6;
  const int l15 = lane & 15, lg = lane >> 4;
  const size_t base = (size_t)b * S_LEN * 3072 + h * 64;
  const unsigned short* qp = qkv + base;
  const unsigned short* kp = qkv + base + 1024;
  const unsigned short* vp = qkv + base + 2048;

  // Q as B-fragment: col=l15=q_local, k-contig 8 at d=lg*8 (+32 for half 1)
  const int qrow = q0 + wid * 16 + l15;
  const bf16x8 qf0 = *(const bf16x8*)(qp + (size_t)qrow * 3072 + lg * 8);
  const bf16x8 qf1 = *(const bf16x8*)(qp + (size_t)qrow * 3072 + 32 + lg * 8);

  f32x4 acc[4];  // O^T: acc[nt][r] = O[q=l15][hd = nt*16 + lg*4 + r]
#pragma unroll
  for (int nt = 0; nt < 4; ++nt) acc[nt] = (f32x4)0.0f;
  float mrow = -3e38f, lrow = 0.0f;

  const int vkey = tid >> 3, vchunk = tid & 7;

  for (int kt = 0; kt < S_LEN / 32; ++kt) {
    __syncthreads();  // WAR: previous tile's Vt reads complete
    // stage V^T tile (round-2 validated): V[kt*32+key][hd] -> Vt[hd][key]
    {
      const bf16x8 vv =
          *(const bf16x8*)(vp + (size_t)(kt * 32 + vkey) * 3072 + vchunk * 8);
#pragma unroll
      for (int j = 0; j < 8; ++j) Vt[vchunk * 8 + j][vkey] = (unsigned short)vv[j];
    }
    // swapped QK^T: D[key][q], col=l15=q, row=4lg+r=key (+16 for s1)
    const size_t kr0 = (size_t)(kt * 32 + l15) * 3072;
    const size_t kr1 = kr0 + (size_t)16 * 3072;
    const bf16x8 k00 = *(const bf16x8*)(kp + kr0 + lg * 8);
    const bf16x8 k01 = *(const bf16x8*)(kp + kr0 + 32 + lg * 8);
    const bf16x8 k10 = *(const bf16x8*)(kp + kr1 + lg * 8);
    const bf16x8 k11 = *(const bf16x8*)(kp + kr1 + 32 + lg * 8);
    f32x4 s0 = (f32x4)0.0f, s1 = (f32x4)0.0f;
    s0 = mfma16(k00, qf0, s0);
    s0 = mfma16(k01, qf1, s0);
    s1 = mfma16(k10, qf0, s1);
    s1 = mfma16(k11, qf1, s1);

    // lane-local softmax over this lane's 8 S-values (all same q=l15)
    float x[8];
#pragma unroll
    for (int r = 0; r < 4; ++r) {
      x[r] = s0[r] * 0.125f;
      x[4 + r] = s1[r] * 0.125f;
    }
    float t = fmaxf(fmaxf(fmaxf(x[0], x[1]), fmaxf(x[2], x[3])),
                    fmaxf(fmaxf(x[4], x[5]), fmaxf(x[6], x[7])));
    t = fmaxf(t, __shfl_xor(t, 16));
    t = fmaxf(t, __shfl_xor(t, 32));
    const float mn = fmaxf(mrow, t);
    const float al = __expf(mrow - mn);
    mrow = mn;
    float p[8];
    float rs = 0.0f;
#pragma unroll
    for (int i = 0; i < 8; ++i) {
      p[i] = __expf(x[i] - mn);
      rs += p[i];
    }
    rs += __shfl_xor(rs, 16);
    rs += __shfl_xor(rs, 32);
    lrow = lrow * al + rs;

    // pack P to bf16 pairs: a0=pair 2lg, a1=pair 2lg+1, b0=pair 8+2lg, b1=pair 9+2lg
    const unsigned a0 = cvtpk_bf16(p[0], p[1]);
    const unsigned a1 = cvtpk_bf16(p[2], p[3]);
    const unsigned b0 = cvtpk_bf16(p[4], p[5]);
    const unsigned b1 = cvtpk_bf16(p[6], p[7]);
    // redistribute: lane-group g needs pairs 4g..4g+3 of its own q=l15
    const int sA = l15 + ((lg & 1) << 5);
    const int sB = sA + 16;
    const unsigned wa0 = __shfl((int)a0, sA), wa1 = __shfl((int)a1, sA);
    const unsigned wa2 = __shfl((int)a0, sB), wa3 = __shfl((int)a1, sB);
    const unsigned wb0 = __shfl((int)b0, sA), wb1 = __shfl((int)b1, sA);
    const unsigned wb2 = __shfl((int)b0, sB), wb3 = __shfl((int)b1, sB);
    const bool hi2 = (lg >= 2);
    u32x4 pw;
    pw[0] = hi2 ? wb0 : wa0;
    pw[1] = hi2 ? wb1 : wa1;
    pw[2] = hi2 ? wb2 : wa2;
    pw[3] = hi2 ? wb3 : wa3;
    const bf16x8 pfrag = __builtin_bit_cast(bf16x8, pw);

    __syncthreads();  // Vt staged & visible

    // rescale O^T
#pragma unroll
    for (int nt = 0; nt < 4; ++nt) {
      f32x4 tacc = acc[nt];
      tacc[0] *= al; tacc[1] *= al; tacc[2] *= al; tacc[3] *= al;
      acc[nt] = tacc;
    }
    // PV: A = V^T frag (row=l15=hd_local, k=8lg+j) from Vt; B = pfrag
#pragma unroll
    for (int nt = 0; nt < 4; ++nt) {
      const bf16x8 vf = *(const bf16x8*)&Vt[nt * 16 + l15][lg * 8];
      acc[nt] = mfma16(vf, pfrag, acc[nt]);
    }
  }

  // epilogue: lane-local 1/lrow, write O
  const float inv = 1.0f / lrow;
  const size_t orow = (size_t)(b * S_LEN + qrow) * 1024 + h * 64;
#pragma unroll
  for (int nt = 0; nt < 4; ++nt) {
#pragma unroll
    for (int r = 0; r < 4; ++r) {
      ctx[orow + nt * 16 + lg * 4 + r] = f2bf(acc[nt][r] * inv);
    }
  }
}

// ---------------------------------------------------------------------------
extern "C" void kernel_launch(void* const* d_in, const int* in_sizes, int n_in,
                              void* d_out, int out_size, void* d_ws, size_t ws_size,
                              hipStream_t stream) {
  const float* x   = (const float*)d_in[0];
  const float* n1g = (const float*)d_in[1];
  const float* n1b = (const float*)d_in[2];
  const float* wq  = (const float*)d_in[3];
  const float* bq  = (const float*)d_in[4];
  const float* wk  = (const float*)d_in[5];
  const float* bk  = (const float*)d_in[6];
  const float* wv  = (const float*)d_in[7];
  const float* bv  = (const float*)d_in[8];
  const float* wo  = (const float*)d_in[9];
  const float* bo  = (const float*)d_in[10];
  const float* ls1 = (const float*)d_in[11];
  const float* n2g = (const float*)d_in[12];
  const float* n2b = (const float*)d_in[13];
  const float* w1  = (const float*)d_in[14];
  const float* b1  = (const float*)d_in[15];
  const float* w2  = (const float*)d_in[16];
  const float* b2  = (const float*)d_in[17];
  const float* ls2 = (const float*)d_in[18];
  float* out = (float*)d_out;

  char* ws = (char*)d_ws;
  unsigned short* wqkvt = (unsigned short*)(ws + 0);          // [3072][1024] 6MB
  unsigned short* wot   = (unsigned short*)(ws + 6291456);    // [1024][1024] 2MB
  unsigned short* w1t   = (unsigned short*)(ws + 8388608);    // [4096][1024] 8MB
  unsigned short* w2t   = (unsigned short*)(ws + 16777216);   // [1024][4096] 8MB
  unsigned short* xn    = (unsigned short*)(ws + 25165824);   // [M][1024] 36MB
  unsigned short* qkvb  = (unsigned short*)(ws + 62914560);   // [M][3072] 108MB
  unsigned short* yn    = (unsigned short*)(ws + 176160768);  // [M][1024] 36MB
  float*          bqkv  = (float*)(ws + 176160768);           // aliases yn (dead before LN2)
  unsigned short* ctx   = xn;   // xn dead after QKV
  unsigned short* hbuf  = xn;   // [M][4096] spans xn+qkvb (both dead by W1)
  (void)ws_size; (void)in_sizes; (void)n_in; (void)out_size;

  const dim3 blk(256);
  concat3_kernel<<<dim3(12), blk, 0, stream>>>(bq, bk, bv, bqkv);
  transpose_cast_kernel<<<dim3(32, 32), blk, 0, stream>>>(wq, wqkvt, 1024, 1024);
  transpose_cast_kernel<<<dim3(32, 32), blk, 0, stream>>>(wk, wqkvt + 1024 * 1024, 1024, 1024);
  transpose_cast_kernel<<<dim3(32, 32), blk, 0, stream>>>(wv, wqkvt + 2048 * 1024, 1024, 1024);
  transpose_cast_kernel<<<dim3(32, 32), blk, 0, stream>>>(wo, wot, 1024, 1024);
  transpose_cast_kernel<<<dim3(128, 32), blk, 0, stream>>>(w1, w1t, 1024, 4096);
  transpose_cast_kernel<<<dim3(32, 128), blk, 0, stream>>>(w2, w2t, 4096, 1024);
  ln_kernel<<<dim3(M_ROWS), blk, 0, stream>>>(x, n1g, n1b, xn);
  // fused QKV: [M][1024] @ [1024][3072] -> [M][3072]
  gemm256<EPI_BF16_BIAS><<<dim3(72 * 12), dim3(512), 0, stream>>>(
      xn, wqkvt, 1024, 3072, 12, bqkv, nullptr, nullptr, qkvb, nullptr);
  attn_kernel<<<dim3(9, 512), blk, 0, stream>>>(qkvb, ctx);
  // WO + ls1 + residual -> d_out (f32)
  gemm256<EPI_F32_RES><<<dim3(72 * 4), dim3(512), 0, stream>>>(
      ctx, wot, 1024, 1024, 4, bo, ls1, x, nullptr, out);
  ln_kernel<<<dim3(M_ROWS), blk, 0, stream>>>(out, n2g, n2b, yn);
  // W1 + exact GELU -> hbuf (bf16)
  gemm256<EPI_GELU><<<dim3(72 * 16), dim3(512), 0, stream>>>(
      yn, w1t, 1024, 4096, 16, b1, nullptr, nullptr, hbuf, nullptr);
  // W2 + ls2 + residual(d_out) -> d_out
  gemm256<EPI_F32_RES><<<dim3(72 * 4), dim3(512), 0, stream>>>(
      hbuf, w2t, 4096, 1024, 4, b2, ls2, out, nullptr, out);
}